// Round 1
// baseline (397.620 us; speedup 1.0000x reference)
//
#include <hip/hip_runtime.h>
#include <cstdint>
#include <cstddef>

#define N_NODES 16384
#define E_EDGES 262144
#define FIN     128
#define DIM     64
#define HID     256
#define NEG     0.2f

// ---------------------------------------------------------------------------
// CSR build: histogram -> scan -> scatter
// ---------------------------------------------------------------------------
__global__ __launch_bounds__(256) void hist_kernel(const int* __restrict__ dst,
                                                   int* __restrict__ cnt) {
    int i = blockIdx.x * 256 + threadIdx.x;
    if (i < E_EDGES) atomicAdd(&cnt[dst[i]], 1);
}

__global__ __launch_bounds__(256) void csr_scan_kernel(const int* __restrict__ cnt,
                                                       int* __restrict__ offs,
                                                       int* __restrict__ cursor) {
    __shared__ int bs[256];
    __shared__ int psum[257];
    int tid = threadIdx.x;              // 256 threads, each scans 64 counts
    int base = tid * 64;
    int s = 0;
    for (int i = 0; i < 64; ++i) s += cnt[base + i];
    bs[tid] = s;
    __syncthreads();
    if (tid == 0) {
        int r = 0;
        for (int i = 0; i < 256; ++i) { psum[i] = r; r += bs[i]; }
        psum[256] = r;
    }
    __syncthreads();
    int run = psum[tid];
    for (int i = 0; i < 64; ++i) {
        int c = cnt[base + i];
        offs[base + i] = run;
        cursor[base + i] = run;
        run += c;
    }
    if (tid == 255) offs[N_NODES] = run;
}

__global__ __launch_bounds__(256) void scatter_kernel(const int* __restrict__ src,
                                                      const int* __restrict__ dst,
                                                      int* __restrict__ cursor,
                                                      int* __restrict__ esrc) {
    int i = blockIdx.x * 256 + threadIdx.x;
    if (i < E_EDGES) {
        int p = atomicAdd(&cursor[dst[i]], 1);
        esrc[p] = src[i];
    }
}

// ---------------------------------------------------------------------------
// Generic fp32 GEMM: C[N,M] = act(A[N,K] @ W[K,M] + bias)
// tile 64x64, BK=16, block 256 threads, 4x4 micro-tile per thread.
// Requires N%64==0, M%64==0, K%16==0 (true for all uses here).
// ---------------------------------------------------------------------------
template<bool RELU, bool HASB>
__global__ __launch_bounds__(256) void gemm_kernel(const float* __restrict__ A,
                                                   const float* __restrict__ W,
                                                   const float* __restrict__ bias,
                                                   float* __restrict__ C,
                                                   int K, int M) {
    __shared__ float As[16][65];   // [k][row], padded to kill store conflicts
    __shared__ float Bs[16][64];   // [k][col]
    int tid = threadIdx.x;
    int rowBase = blockIdx.x * 64;
    int colBase = blockIdx.y * 64;
    int tx = tid & 15, ty = tid >> 4;

    int ar = tid >> 2;            // 0..63 (row within tile)
    int ak = (tid & 3) * 4;       // 0,4,8,12
    int bk = tid >> 4;            // 0..15
    int bm = (tid & 15) * 4;      // 0..60

    float acc[4][4] = {};
    for (int kb = 0; kb < K; kb += 16) {
        float4 a4 = *(const float4*)(A + (size_t)(rowBase + ar) * K + kb + ak);
        As[ak + 0][ar] = a4.x; As[ak + 1][ar] = a4.y;
        As[ak + 2][ar] = a4.z; As[ak + 3][ar] = a4.w;
        float4 b4 = *(const float4*)(W + (size_t)(kb + bk) * M + colBase + bm);
        *(float4*)&Bs[bk][bm] = b4;
        __syncthreads();
#pragma unroll
        for (int k = 0; k < 16; ++k) {
            float a[4], b[4];
#pragma unroll
            for (int i = 0; i < 4; ++i) a[i] = As[k][ty * 4 + i];
#pragma unroll
            for (int j = 0; j < 4; ++j) b[j] = Bs[k][tx * 4 + j];
#pragma unroll
            for (int i = 0; i < 4; ++i)
#pragma unroll
                for (int j = 0; j < 4; ++j) acc[i][j] += a[i] * b[j];
        }
        __syncthreads();
    }
#pragma unroll
    for (int i = 0; i < 4; ++i) {
#pragma unroll
        for (int j = 0; j < 4; ++j) {
            int col = colBase + tx * 4 + j;
            float v = acc[i][j];
            if (HASB) v += bias[col];
            if (RELU) v = fmaxf(v, 0.f);
            C[(size_t)(rowBase + ty * 4 + i) * M + col] = v;
        }
    }
}

// ---------------------------------------------------------------------------
// GATv2 edge-softmax + aggregate, fused epilogue:
//   out[n,:] = relu( (sum_e alpha_e * xl[src_e]) + bias ) + resid[n,:]
// One wave per dst node; lane owns 4 consecutive dims (float4).
// H=4: per-head (16-lane group) softmax; H=1: whole-wave softmax.
// ---------------------------------------------------------------------------
template<int H>
__global__ __launch_bounds__(256) void gat_agg_kernel(const float* __restrict__ xl,
                                                      const float* __restrict__ xr,
                                                      const float* __restrict__ att,
                                                      const float* __restrict__ bias,
                                                      const float* __restrict__ resid,
                                                      const int* __restrict__ offs,
                                                      const int* __restrict__ esrc,
                                                      float* __restrict__ out) {
    int wid = threadIdx.x >> 6;
    int lane = threadIdx.x & 63;
    int node = blockIdx.x * 4 + wid;

    const float4* xl4 = (const float4*)xl;
    float4 xrv = ((const float4*)xr)[(size_t)node * 64 + lane];
    float4 av = ((const float4*)att)[lane];

    float m = -1e30f, s = 0.f;
    float4 acc = make_float4(0.f, 0.f, 0.f, 0.f);

    auto proc = [&](int src) {
        float4 xlv = xl4[(size_t)src * 64 + lane];
        float ex = xlv.x + xrv.x; ex = ex > 0.f ? ex : NEG * ex;
        float ey = xlv.y + xrv.y; ey = ey > 0.f ? ey : NEG * ey;
        float ez = xlv.z + xrv.z; ez = ez > 0.f ? ez : NEG * ez;
        float ew = xlv.w + xrv.w; ew = ew > 0.f ? ew : NEG * ew;
        float lp = ex * av.x + ey * av.y + ez * av.z + ew * av.w;
        lp += __shfl_xor(lp, 1);
        lp += __shfl_xor(lp, 2);
        lp += __shfl_xor(lp, 4);
        lp += __shfl_xor(lp, 8);
        if constexpr (H == 1) {
            lp += __shfl_xor(lp, 16);
            lp += __shfl_xor(lp, 32);
        }
        float mn = fmaxf(m, lp);
        float c = __expf(m - mn);
        float p = __expf(lp - mn);
        s = s * c + p;
        acc.x = acc.x * c + p * xlv.x;
        acc.y = acc.y * c + p * xlv.y;
        acc.z = acc.z * c + p * xlv.z;
        acc.w = acc.w * c + p * xlv.w;
        m = mn;
    };

    proc(node);                               // self-loop
    int e0 = offs[node], e1 = offs[node + 1];
    for (int e = e0; e < e1; ++e) proc(esrc[e]);

    float inv = 1.f / s;
    float4 bv = ((const float4*)bias)[lane];
    float4 rv = ((const float4*)resid)[(size_t)node * 64 + lane];
    float4 o;
    o.x = fmaxf(acc.x * inv + bv.x, 0.f) + rv.x;
    o.y = fmaxf(acc.y * inv + bv.y, 0.f) + rv.y;
    o.z = fmaxf(acc.z * inv + bv.z, 0.f) + rv.z;
    o.w = fmaxf(acc.w * inv + bv.w, 0.f) + rv.w;
    ((float4*)out)[(size_t)node * 64 + lane] = o;
}

// ---------------------------------------------------------------------------
// Final projection: out[n] = A[n,:64] . w + b   (wave per row)
// ---------------------------------------------------------------------------
__global__ __launch_bounds__(256) void mlp_final_kernel(const float* __restrict__ A,
                                                        const float* __restrict__ w,
                                                        const float* __restrict__ b,
                                                        float* __restrict__ out) {
    int wid = threadIdx.x >> 6;
    int lane = threadIdx.x & 63;
    int node = blockIdx.x * 4 + wid;
    float v = A[(size_t)node * 64 + lane] * w[lane];
    v += __shfl_xor(v, 1);
    v += __shfl_xor(v, 2);
    v += __shfl_xor(v, 4);
    v += __shfl_xor(v, 8);
    v += __shfl_xor(v, 16);
    v += __shfl_xor(v, 32);
    if (lane == 0) out[node] = v + b[0];
}

// ---------------------------------------------------------------------------
extern "C" void kernel_launch(void* const* d_in, const int* in_sizes, int n_in,
                              void* d_out, int out_size, void* d_ws, size_t ws_size,
                              hipStream_t stream) {
    const float* x     = (const float*)d_in[0];
    const int*   ei    = (const int*)d_in[1];
    const float* Win   = (const float*)d_in[2];
    const float* b_in  = (const float*)d_in[3];
    const float* Wskip = (const float*)d_in[4];
    const float* bskip = (const float*)d_in[5];
    const float* Wl1   = (const float*)d_in[6];
    const float* Wr1   = (const float*)d_in[7];
    const float* att1  = (const float*)d_in[8];
    const float* b1    = (const float*)d_in[9];
    const float* Wl2   = (const float*)d_in[10];
    const float* Wr2   = (const float*)d_in[11];
    const float* att2  = (const float*)d_in[12];
    const float* b2    = (const float*)d_in[13];
    const float* Wl3   = (const float*)d_in[14];
    const float* Wr3   = (const float*)d_in[15];
    const float* att3  = (const float*)d_in[16];
    const float* b3    = (const float*)d_in[17];
    const float* Wm1   = (const float*)d_in[18];
    const float* bm1   = (const float*)d_in[19];
    const float* Wm2   = (const float*)d_in[20];
    const float* bm2   = (const float*)d_in[21];
    const float* Wm3   = (const float*)d_in[22];
    const float* bm3   = (const float*)d_in[23];

    // workspace layout (floats)
    float* ws   = (float*)d_ws;
    float* h    = ws;                                   // N x 64
    float* xl   = h    + (size_t)N_NODES * DIM;         // N x 256
    float* xr   = xl   + (size_t)N_NODES * HID;         // N x 256
    float* skip = xr   + (size_t)N_NODES * HID;         // N x 256 (later: out3)
    float* bufA = skip + (size_t)N_NODES * HID;         // N x 256 (out1)
    float* bufB = bufA + (size_t)N_NODES * HID;         // N x 256 (out2)
    int* cnt    = (int*)(bufB + (size_t)N_NODES * HID);
    int* offs   = cnt + N_NODES;
    int* cursor = offs + N_NODES + 1;
    int* esrc   = cursor + N_NODES;

    const int* src = ei;
    const int* dst = ei + E_EDGES;

    // ---- CSR build ----
    hipMemsetAsync(cnt, 0, N_NODES * sizeof(int), stream);
    hist_kernel<<<E_EDGES / 256, 256, 0, stream>>>(dst, cnt);
    csr_scan_kernel<<<1, 256, 0, stream>>>(cnt, offs, cursor);
    scatter_kernel<<<E_EDGES / 256, 256, 0, stream>>>(src, dst, cursor, esrc);

    dim3 g1(N_NODES / 64, 1), g4(N_NODES / 64, 4);

    // ---- input proj: h = relu(x @ Win + b_in) ----
    gemm_kernel<true, true><<<g1, 256, 0, stream>>>(x, Win, b_in, h, FIN, DIM);

    // ---- conv1 prep ----
    gemm_kernel<false, false><<<g4, 256, 0, stream>>>(h, Wl1, nullptr, xl, DIM, HID);
    gemm_kernel<false, false><<<g4, 256, 0, stream>>>(h, Wr1, nullptr, xr, DIM, HID);
    gemm_kernel<false, true><<<g4, 256, 0, stream>>>(h, Wskip, bskip, skip, DIM, HID);
    // out1 = relu(gat1 + b1) + skip
    gat_agg_kernel<4><<<N_NODES / 4, 256, 0, stream>>>(xl, xr, att1, b1, skip, offs, esrc, bufA);

    // ---- conv2 ----
    gemm_kernel<false, false><<<g4, 256, 0, stream>>>(bufA, Wl2, nullptr, xl, HID, HID);
    gemm_kernel<false, false><<<g4, 256, 0, stream>>>(bufA, Wr2, nullptr, xr, HID, HID);
    gat_agg_kernel<1><<<N_NODES / 4, 256, 0, stream>>>(xl, xr, att2, b2, bufA, offs, esrc, bufB);

    // ---- conv3 ----
    gemm_kernel<false, false><<<g4, 256, 0, stream>>>(bufB, Wl3, nullptr, xl, HID, HID);
    gemm_kernel<false, false><<<g4, 256, 0, stream>>>(bufB, Wr3, nullptr, xr, HID, HID);
    gat_agg_kernel<1><<<N_NODES / 4, 256, 0, stream>>>(xl, xr, att3, b3, bufB, offs, esrc, skip); // out3 -> skip

    // ---- MLP head ----
    gemm_kernel<true, true><<<g1, 256, 0, stream>>>(skip, Wm1, bm1, h, HID, DIM);   // t1 -> h
    gemm_kernel<true, true><<<g1, 256, 0, stream>>>(h, Wm2, bm2, xl, DIM, DIM);     // t2 -> xl
    mlp_final_kernel<<<N_NODES / 4, 256, 0, stream>>>(xl, Wm3, bm3, (float*)d_out);
}

// Round 2
// 343.967 us; speedup vs baseline: 1.1560x; 1.1560x over previous
//
#include <hip/hip_runtime.h>
#include <cstdint>
#include <cstddef>

#define N_NODES 16384
#define E_EDGES 262144
#define FIN     128
#define DIM     64
#define HID     256
#define NEG     0.2f

// ---------------------------------------------------------------------------
// CSR build: histogram -> scan -> scatter
// ---------------------------------------------------------------------------
__global__ __launch_bounds__(256) void hist_kernel(const int* __restrict__ dst,
                                                   int* __restrict__ cnt) {
    int i = blockIdx.x * 256 + threadIdx.x;
    if (i < E_EDGES) atomicAdd(&cnt[dst[i]], 1);
}

__global__ __launch_bounds__(256) void csr_scan_kernel(const int* __restrict__ cnt,
                                                       int* __restrict__ offs,
                                                       int* __restrict__ cursor) {
    __shared__ int bs[256];
    __shared__ int psum[257];
    int tid = threadIdx.x;              // 256 threads, each scans 64 counts
    int base = tid * 64;
    int s = 0;
    for (int i = 0; i < 64; ++i) s += cnt[base + i];
    bs[tid] = s;
    __syncthreads();
    if (tid == 0) {
        int r = 0;
        for (int i = 0; i < 256; ++i) { psum[i] = r; r += bs[i]; }
        psum[256] = r;
    }
    __syncthreads();
    int run = psum[tid];
    for (int i = 0; i < 64; ++i) {
        int c = cnt[base + i];
        offs[base + i] = run;
        cursor[base + i] = run;
        run += c;
    }
    if (tid == 255) offs[N_NODES] = run;
}

__global__ __launch_bounds__(256) void scatter_kernel(const int* __restrict__ src,
                                                      const int* __restrict__ dst,
                                                      int* __restrict__ cursor,
                                                      int* __restrict__ esrc) {
    int i = blockIdx.x * 256 + threadIdx.x;
    if (i < E_EDGES) {
        int p = atomicAdd(&cursor[dst[i]], 1);
        esrc[p] = src[i];
    }
}

// ---------------------------------------------------------------------------
// Generic fp32 GEMM: C[N,M] = act(A[N,K] @ W[K,M] + bias)
// tile 64x64, BK=16, block 256 threads, 4x4 micro-tile, float4 LDS reads.
// ---------------------------------------------------------------------------
template<bool RELU, bool HASB>
__global__ __launch_bounds__(256) void gemm_kernel(const float* __restrict__ A,
                                                   const float* __restrict__ W,
                                                   const float* __restrict__ bias,
                                                   float* __restrict__ C,
                                                   int K, int M) {
    __shared__ float As[16][68];   // [k][row], stride 68 keeps 16B alignment
    __shared__ float Bs[16][64];   // [k][col]
    int tid = threadIdx.x;
    int rowBase = blockIdx.x * 64;
    int colBase = blockIdx.y * 64;
    int tx = tid & 15, ty = tid >> 4;

    int ar = tid >> 2;            // 0..63 (row within tile)
    int ak = (tid & 3) * 4;       // 0,4,8,12
    int bk = tid >> 4;            // 0..15
    int bm = (tid & 15) * 4;      // 0..60

    float acc[4][4] = {};
    for (int kb = 0; kb < K; kb += 16) {
        float4 a4 = *(const float4*)(A + (size_t)(rowBase + ar) * K + kb + ak);
        As[ak + 0][ar] = a4.x; As[ak + 1][ar] = a4.y;
        As[ak + 2][ar] = a4.z; As[ak + 3][ar] = a4.w;
        float4 b4 = *(const float4*)(W + (size_t)(kb + bk) * M + colBase + bm);
        *(float4*)&Bs[bk][bm] = b4;
        __syncthreads();
#pragma unroll
        for (int k = 0; k < 16; ++k) {
            float4 a4r = *(const float4*)&As[k][ty * 4];
            float4 b4r = *(const float4*)&Bs[k][tx * 4];
            float a[4] = {a4r.x, a4r.y, a4r.z, a4r.w};
            float b[4] = {b4r.x, b4r.y, b4r.z, b4r.w};
#pragma unroll
            for (int i = 0; i < 4; ++i)
#pragma unroll
                for (int j = 0; j < 4; ++j) acc[i][j] += a[i] * b[j];
        }
        __syncthreads();
    }
#pragma unroll
    for (int i = 0; i < 4; ++i) {
#pragma unroll
        for (int j = 0; j < 4; ++j) {
            int col = colBase + tx * 4 + j;
            float v = acc[i][j];
            if (HASB) v += bias[col];
            if (RELU) v = fmaxf(v, 0.f);
            C[(size_t)(rowBase + ty * 4 + i) * M + col] = v;
        }
    }
}

// ---------------------------------------------------------------------------
// Dual-output GEMM sharing the A tile: C1 = A@W1, C2 = A@W2 (no bias/act).
// ---------------------------------------------------------------------------
__global__ __launch_bounds__(256) void gemm_dual_kernel(const float* __restrict__ A,
                                                        const float* __restrict__ W1,
                                                        const float* __restrict__ W2,
                                                        float* __restrict__ C1,
                                                        float* __restrict__ C2,
                                                        int K, int M) {
    __shared__ float As[16][68];
    __shared__ float Bs1[16][64];
    __shared__ float Bs2[16][64];
    int tid = threadIdx.x;
    int rowBase = blockIdx.x * 64;
    int colBase = blockIdx.y * 64;
    int tx = tid & 15, ty = tid >> 4;

    int ar = tid >> 2;
    int ak = (tid & 3) * 4;
    int bk = tid >> 4;
    int bm = (tid & 15) * 4;

    float acc1[4][4] = {}, acc2[4][4] = {};
    for (int kb = 0; kb < K; kb += 16) {
        float4 a4 = *(const float4*)(A + (size_t)(rowBase + ar) * K + kb + ak);
        As[ak + 0][ar] = a4.x; As[ak + 1][ar] = a4.y;
        As[ak + 2][ar] = a4.z; As[ak + 3][ar] = a4.w;
        *(float4*)&Bs1[bk][bm] = *(const float4*)(W1 + (size_t)(kb + bk) * M + colBase + bm);
        *(float4*)&Bs2[bk][bm] = *(const float4*)(W2 + (size_t)(kb + bk) * M + colBase + bm);
        __syncthreads();
#pragma unroll
        for (int k = 0; k < 16; ++k) {
            float4 a4r = *(const float4*)&As[k][ty * 4];
            float4 b14 = *(const float4*)&Bs1[k][tx * 4];
            float4 b24 = *(const float4*)&Bs2[k][tx * 4];
            float a[4] = {a4r.x, a4r.y, a4r.z, a4r.w};
            float b1[4] = {b14.x, b14.y, b14.z, b14.w};
            float b2[4] = {b24.x, b24.y, b24.z, b24.w};
#pragma unroll
            for (int i = 0; i < 4; ++i)
#pragma unroll
                for (int j = 0; j < 4; ++j) {
                    acc1[i][j] += a[i] * b1[j];
                    acc2[i][j] += a[i] * b2[j];
                }
        }
        __syncthreads();
    }
#pragma unroll
    for (int i = 0; i < 4; ++i)
#pragma unroll
        for (int j = 0; j < 4; ++j) {
            size_t idx = (size_t)(rowBase + ty * 4 + i) * M + colBase + tx * 4 + j;
            C1[idx] = acc1[i][j];
            C2[idx] = acc2[i][j];
        }
}

// ---------------------------------------------------------------------------
// GATv2 edge-softmax + aggregate, 4-edge-unrolled online softmax.
//   out[n,:] = relu( (sum_e alpha_e * xl[src_e]) + bias ) + resid[n,:]
// One wave per dst node; lane owns 4 consecutive dims (float4).
// H=4: per-head (16-lane group) softmax; H=1: whole-wave softmax.
// ---------------------------------------------------------------------------
template<int H>
__global__ __launch_bounds__(256) void gat_agg_kernel(const float* __restrict__ xl,
                                                      const float* __restrict__ xr,
                                                      const float* __restrict__ att,
                                                      const float* __restrict__ bias,
                                                      const float* __restrict__ resid,
                                                      const int* __restrict__ offs,
                                                      const int* __restrict__ esrc,
                                                      float* __restrict__ out) {
    int wid = threadIdx.x >> 6;
    int lane = threadIdx.x & 63;
    int node = blockIdx.x * 4 + wid;

    const float4* xl4 = (const float4*)xl;
    float4 xrv = ((const float4*)xr)[(size_t)node * 64 + lane];
    float4 av = ((const float4*)att)[lane];

    float m = -1e30f, s = 0.f;
    float4 acc = make_float4(0.f, 0.f, 0.f, 0.f);

    auto logit = [&](const float4& xlv) -> float {
        float ex = xlv.x + xrv.x; ex = ex > 0.f ? ex : NEG * ex;
        float ey = xlv.y + xrv.y; ey = ey > 0.f ? ey : NEG * ey;
        float ez = xlv.z + xrv.z; ez = ez > 0.f ? ez : NEG * ez;
        float ew = xlv.w + xrv.w; ew = ew > 0.f ? ew : NEG * ew;
        float lp = ex * av.x + ey * av.y + ez * av.z + ew * av.w;
        lp += __shfl_xor(lp, 1);
        lp += __shfl_xor(lp, 2);
        lp += __shfl_xor(lp, 4);
        lp += __shfl_xor(lp, 8);
        if constexpr (H == 1) {
            lp += __shfl_xor(lp, 16);
            lp += __shfl_xor(lp, 32);
        }
        return lp;
    };

    auto single = [&](int src) {
        float4 xlv = xl4[(size_t)src * 64 + lane];
        float lp = logit(xlv);
        float mn = fmaxf(m, lp);
        float c = __expf(m - mn);
        float p = __expf(lp - mn);
        s = s * c + p;
        acc.x = acc.x * c + p * xlv.x;
        acc.y = acc.y * c + p * xlv.y;
        acc.z = acc.z * c + p * xlv.z;
        acc.w = acc.w * c + p * xlv.w;
        m = mn;
    };

    single(node);                             // self-loop
    int e0 = offs[node], e1 = offs[node + 1];
    int e = e0;
    for (; e + 4 <= e1; e += 4) {
        int s0 = esrc[e], s1 = esrc[e + 1], s2 = esrc[e + 2], s3 = esrc[e + 3];
        float4 x0 = xl4[(size_t)s0 * 64 + lane];
        float4 x1 = xl4[(size_t)s1 * 64 + lane];
        float4 x2 = xl4[(size_t)s2 * 64 + lane];
        float4 x3 = xl4[(size_t)s3 * 64 + lane];
        float lp0 = logit(x0);
        float lp1 = logit(x1);
        float lp2 = logit(x2);
        float lp3 = logit(x3);
        float mn = fmaxf(fmaxf(fmaxf(lp0, lp1), fmaxf(lp2, lp3)), m);
        float c  = __expf(m - mn);
        float p0 = __expf(lp0 - mn);
        float p1 = __expf(lp1 - mn);
        float p2 = __expf(lp2 - mn);
        float p3 = __expf(lp3 - mn);
        s = s * c + ((p0 + p1) + (p2 + p3));
        acc.x = acc.x * c + ((p0 * x0.x + p1 * x1.x) + (p2 * x2.x + p3 * x3.x));
        acc.y = acc.y * c + ((p0 * x0.y + p1 * x1.y) + (p2 * x2.y + p3 * x3.y));
        acc.z = acc.z * c + ((p0 * x0.z + p1 * x1.z) + (p2 * x2.z + p3 * x3.z));
        acc.w = acc.w * c + ((p0 * x0.w + p1 * x1.w) + (p2 * x2.w + p3 * x3.w));
        m = mn;
    }
    for (; e < e1; ++e) single(esrc[e]);

    float inv = 1.f / s;
    float4 bv = ((const float4*)bias)[lane];
    float4 rv = ((const float4*)resid)[(size_t)node * 64 + lane];
    float4 o;
    o.x = fmaxf(acc.x * inv + bv.x, 0.f) + rv.x;
    o.y = fmaxf(acc.y * inv + bv.y, 0.f) + rv.y;
    o.z = fmaxf(acc.z * inv + bv.z, 0.f) + rv.z;
    o.w = fmaxf(acc.w * inv + bv.w, 0.f) + rv.w;
    ((float4*)out)[(size_t)node * 64 + lane] = o;
}

// ---------------------------------------------------------------------------
// Final projection: out[n] = A[n,:64] . w + b   (wave per row)
// ---------------------------------------------------------------------------
__global__ __launch_bounds__(256) void mlp_final_kernel(const float* __restrict__ A,
                                                        const float* __restrict__ w,
                                                        const float* __restrict__ b,
                                                        float* __restrict__ out) {
    int wid = threadIdx.x >> 6;
    int lane = threadIdx.x & 63;
    int node = blockIdx.x * 4 + wid;
    float v = A[(size_t)node * 64 + lane] * w[lane];
    v += __shfl_xor(v, 1);
    v += __shfl_xor(v, 2);
    v += __shfl_xor(v, 4);
    v += __shfl_xor(v, 8);
    v += __shfl_xor(v, 16);
    v += __shfl_xor(v, 32);
    if (lane == 0) out[node] = v + b[0];
}

// ---------------------------------------------------------------------------
extern "C" void kernel_launch(void* const* d_in, const int* in_sizes, int n_in,
                              void* d_out, int out_size, void* d_ws, size_t ws_size,
                              hipStream_t stream) {
    const float* x     = (const float*)d_in[0];
    const int*   ei    = (const int*)d_in[1];
    const float* Win   = (const float*)d_in[2];
    const float* b_in  = (const float*)d_in[3];
    const float* Wskip = (const float*)d_in[4];
    const float* bskip = (const float*)d_in[5];
    const float* Wl1   = (const float*)d_in[6];
    const float* Wr1   = (const float*)d_in[7];
    const float* att1  = (const float*)d_in[8];
    const float* b1    = (const float*)d_in[9];
    const float* Wl2   = (const float*)d_in[10];
    const float* Wr2   = (const float*)d_in[11];
    const float* att2  = (const float*)d_in[12];
    const float* b2    = (const float*)d_in[13];
    const float* Wl3   = (const float*)d_in[14];
    const float* Wr3   = (const float*)d_in[15];
    const float* att3  = (const float*)d_in[16];
    const float* b3    = (const float*)d_in[17];
    const float* Wm1   = (const float*)d_in[18];
    const float* bm1   = (const float*)d_in[19];
    const float* Wm2   = (const float*)d_in[20];
    const float* bm2   = (const float*)d_in[21];
    const float* Wm3   = (const float*)d_in[22];
    const float* bm3   = (const float*)d_in[23];

    // workspace layout (floats)
    float* ws   = (float*)d_ws;
    float* h    = ws;                                   // N x 64
    float* xl   = h    + (size_t)N_NODES * DIM;         // N x 256
    float* xr   = xl   + (size_t)N_NODES * HID;         // N x 256
    float* skip = xr   + (size_t)N_NODES * HID;         // N x 256 (later: out3)
    float* bufA = skip + (size_t)N_NODES * HID;         // N x 256 (out1)
    float* bufB = bufA + (size_t)N_NODES * HID;         // N x 256 (out2)
    int* cnt    = (int*)(bufB + (size_t)N_NODES * HID);
    int* offs   = cnt + N_NODES;
    int* cursor = offs + N_NODES + 1;
    int* esrc   = cursor + N_NODES;

    const int* src = ei;
    const int* dst = ei + E_EDGES;

    // ---- CSR build ----
    hipMemsetAsync(cnt, 0, N_NODES * sizeof(int), stream);
    hist_kernel<<<E_EDGES / 256, 256, 0, stream>>>(dst, cnt);
    csr_scan_kernel<<<1, 256, 0, stream>>>(cnt, offs, cursor);
    scatter_kernel<<<E_EDGES / 256, 256, 0, stream>>>(src, dst, cursor, esrc);

    dim3 g1(N_NODES / 64, 1), g4(N_NODES / 64, 4);

    // ---- input proj: h = relu(x @ Win + b_in) ----
    gemm_kernel<true, true><<<g1, 256, 0, stream>>>(x, Win, b_in, h, FIN, DIM);

    // ---- conv1 prep ----
    gemm_dual_kernel<<<g4, 256, 0, stream>>>(h, Wl1, Wr1, xl, xr, DIM, HID);
    gemm_kernel<false, true><<<g4, 256, 0, stream>>>(h, Wskip, bskip, skip, DIM, HID);
    // out1 = relu(gat1 + b1) + skip
    gat_agg_kernel<4><<<N_NODES / 4, 256, 0, stream>>>(xl, xr, att1, b1, skip, offs, esrc, bufA);

    // ---- conv2 ----
    gemm_dual_kernel<<<g4, 256, 0, stream>>>(bufA, Wl2, Wr2, xl, xr, HID, HID);
    gat_agg_kernel<1><<<N_NODES / 4, 256, 0, stream>>>(xl, xr, att2, b2, bufA, offs, esrc, bufB);

    // ---- conv3 ----
    gemm_dual_kernel<<<g4, 256, 0, stream>>>(bufB, Wl3, Wr3, xl, xr, HID, HID);
    gat_agg_kernel<1><<<N_NODES / 4, 256, 0, stream>>>(xl, xr, att3, b3, bufB, offs, esrc, skip); // out3 -> skip

    // ---- MLP head ----
    gemm_kernel<true, true><<<g1, 256, 0, stream>>>(skip, Wm1, bm1, h, HID, DIM);   // t1 -> h
    gemm_kernel<true, true><<<g1, 256, 0, stream>>>(h, Wm2, bm2, xl, DIM, DIM);     // t2 -> xl
    mlp_final_kernel<<<N_NODES / 4, 256, 0, stream>>>(xl, Wm3, bm3, (float*)d_out);
}

// Round 3
// 238.494 us; speedup vs baseline: 1.6672x; 1.4422x over previous
//
#include <hip/hip_runtime.h>
#include <cstdint>
#include <cstddef>

#define N_NODES 16384
#define E_EDGES 262144
#define FIN     128
#define DIM     64
#define HID     256
#define NEG     0.2f

typedef _Float16 h8 __attribute__((ext_vector_type(8)));
typedef _Float16 h4 __attribute__((ext_vector_type(4)));
typedef float    f32x4 __attribute__((ext_vector_type(4)));

// ---------------------------------------------------------------------------
// CSR build: histogram -> scan -> scatter
// ---------------------------------------------------------------------------
__global__ __launch_bounds__(256) void hist_kernel(const int* __restrict__ dst,
                                                   int* __restrict__ cnt) {
    int i = blockIdx.x * 256 + threadIdx.x;
    if (i < E_EDGES) atomicAdd(&cnt[dst[i]], 1);
}

__global__ __launch_bounds__(256) void csr_scan_kernel(const int* __restrict__ cnt,
                                                       int* __restrict__ offs,
                                                       int* __restrict__ cursor) {
    __shared__ int bs[256];
    __shared__ int psum[257];
    int tid = threadIdx.x;
    int base = tid * 64;
    int s = 0;
    for (int i = 0; i < 64; ++i) s += cnt[base + i];
    bs[tid] = s;
    __syncthreads();
    if (tid == 0) {
        int r = 0;
        for (int i = 0; i < 256; ++i) { psum[i] = r; r += bs[i]; }
        psum[256] = r;
    }
    __syncthreads();
    int run = psum[tid];
    for (int i = 0; i < 64; ++i) {
        int c = cnt[base + i];
        offs[base + i] = run;
        cursor[base + i] = run;
        run += c;
    }
    if (tid == 255) offs[N_NODES] = run;
}

__global__ __launch_bounds__(256) void scatter_kernel(const int* __restrict__ src,
                                                      const int* __restrict__ dst,
                                                      int* __restrict__ cursor,
                                                      int* __restrict__ esrc) {
    int i = blockIdx.x * 256 + threadIdx.x;
    if (i < E_EDGES) {
        int p = atomicAdd(&cursor[dst[i]], 1);
        esrc[p] = src[i];
    }
}

// ---------------------------------------------------------------------------
// Weight pack: fp32 W[Ksrc][Nsrc] -> fp16 Wp[k>>3][NT cols][8] at col offset.
// ---------------------------------------------------------------------------
__global__ __launch_bounds__(256) void pack_w_kernel(const float* __restrict__ W,
                                                     _Float16* __restrict__ Wp,
                                                     int Ksrc, int Nsrc, int NT, int colOff) {
    int i = blockIdx.x * 256 + threadIdx.x;
    if (i < Ksrc * Nsrc) {
        int k = i / Nsrc, n = i % Nsrc;
        Wp[((size_t)(k >> 3) * NT + colOff + n) * 8 + (k & 7)] = (_Float16)W[i];
    }
}

// ---------------------------------------------------------------------------
// fp32 GEMM (kept for input proj + MLP head): C = act(A[N,K] @ W[K,M] + bias)
// tile 64x64, BK=16, 256 thr, 4x4 micro-tile. O16: write fp16 output.
// ---------------------------------------------------------------------------
template<bool RELU, bool HASB, bool O16>
__global__ __launch_bounds__(256) void gemm_kernel(const float* __restrict__ A,
                                                   const float* __restrict__ W,
                                                   const float* __restrict__ bias,
                                                   void* __restrict__ Cv,
                                                   int K, int M) {
    __shared__ float As[16][68];
    __shared__ float Bs[16][64];
    int tid = threadIdx.x;
    int rowBase = blockIdx.x * 64;
    int colBase = blockIdx.y * 64;
    int tx = tid & 15, ty = tid >> 4;

    int ar = tid >> 2;
    int ak = (tid & 3) * 4;
    int bk = tid >> 4;
    int bm = (tid & 15) * 4;

    float acc[4][4] = {};
    for (int kb = 0; kb < K; kb += 16) {
        float4 a4 = *(const float4*)(A + (size_t)(rowBase + ar) * K + kb + ak);
        As[ak + 0][ar] = a4.x; As[ak + 1][ar] = a4.y;
        As[ak + 2][ar] = a4.z; As[ak + 3][ar] = a4.w;
        *(float4*)&Bs[bk][bm] = *(const float4*)(W + (size_t)(kb + bk) * M + colBase + bm);
        __syncthreads();
#pragma unroll
        for (int k = 0; k < 16; ++k) {
            float4 a4r = *(const float4*)&As[k][ty * 4];
            float4 b4r = *(const float4*)&Bs[k][tx * 4];
            float a[4] = {a4r.x, a4r.y, a4r.z, a4r.w};
            float b[4] = {b4r.x, b4r.y, b4r.z, b4r.w};
#pragma unroll
            for (int i = 0; i < 4; ++i)
#pragma unroll
                for (int j = 0; j < 4; ++j) acc[i][j] += a[i] * b[j];
        }
        __syncthreads();
    }
#pragma unroll
    for (int i = 0; i < 4; ++i) {
#pragma unroll
        for (int j = 0; j < 4; ++j) {
            int col = colBase + tx * 4 + j;
            float v = acc[i][j];
            if (HASB) v += bias[col];
            if (RELU) v = fmaxf(v, 0.f);
            size_t idx = (size_t)(rowBase + ty * 4 + i) * M + col;
            if constexpr (O16) ((_Float16*)Cv)[idx] = (_Float16)v;
            else               ((float*)Cv)[idx] = v;
        }
    }
}

// ---------------------------------------------------------------------------
// fp16 MFMA GEMM, no-LDS direct-fragment form.
//   A fp16 [M][K] row-major; Wp fp16 packed [K/8][NT][8].
//   Block = 256 thr = 4 waves (2x2 of 64x64); tile 128 rows x 128 packed cols.
//   Packed cols segment into 256-wide outputs: seg0->o16a, seg1->o16b,
//   seg2->o32 (+bias, fp32) when present.
// MFMA f32_16x16x32_f16 layouts: A row=l&15,k=(l>>4)*8+j; B col=l&15,same k;
// C/D col=l&15,row=(l>>4)*4+q.
// ---------------------------------------------------------------------------
template<int K>
__global__ __launch_bounds__(256) void mfma_gemm_kernel(const _Float16* __restrict__ A,
                                                        const _Float16* __restrict__ Wp,
                                                        int NT,
                                                        _Float16* __restrict__ o16a,
                                                        _Float16* __restrict__ o16b,
                                                        float* __restrict__ o32,
                                                        const float* __restrict__ bias) {
    int tid = threadIdx.x;
    int lane = tid & 63, wid = tid >> 6;
    int wm = wid >> 1, wn = wid & 1;
    int rowBase = blockIdx.x * 128 + wm * 64;
    int colBase = blockIdx.y * 128 + wn * 64;     // global packed col
    int l15 = lane & 15, l4 = lane >> 4;

    f32x4 acc[4][4] = {};

#pragma unroll
    for (int ks = 0; ks < K / 32; ++ks) {
        h8 af[4], bf[4];
#pragma unroll
        for (int mi = 0; mi < 4; ++mi)
            af[mi] = *(const h8*)(A + (size_t)(rowBase + mi * 16 + l15) * K + ks * 32 + l4 * 8);
#pragma unroll
        for (int ni = 0; ni < 4; ++ni)
            bf[ni] = *(const h8*)(Wp + ((size_t)(ks * 4 + l4) * NT + colBase + ni * 16 + l15) * 8);
#pragma unroll
        for (int mi = 0; mi < 4; ++mi)
#pragma unroll
            for (int ni = 0; ni < 4; ++ni)
                acc[mi][ni] = __builtin_amdgcn_mfma_f32_16x16x32_f16(af[mi], bf[ni], acc[mi][ni], 0, 0, 0);
    }

    int seg = colBase >> 8;
    int cbase = colBase & 255;
    if (o32 != nullptr && seg == 2) {
#pragma unroll
        for (int mi = 0; mi < 4; ++mi)
#pragma unroll
            for (int ni = 0; ni < 4; ++ni) {
                int c = cbase + ni * 16 + l15;
                float bv = bias[c];
#pragma unroll
                for (int q = 0; q < 4; ++q) {
                    int r = rowBase + mi * 16 + l4 * 4 + q;
                    o32[(size_t)r * 256 + c] = acc[mi][ni][q] + bv;
                }
            }
    } else {
        _Float16* o = (seg == 0) ? o16a : o16b;
#pragma unroll
        for (int mi = 0; mi < 4; ++mi)
#pragma unroll
            for (int ni = 0; ni < 4; ++ni) {
                int c = cbase + ni * 16 + l15;
#pragma unroll
                for (int q = 0; q < 4; ++q) {
                    int r = rowBase + mi * 16 + l4 * 4 + q;
                    o[(size_t)r * 256 + c] = (_Float16)acc[mi][ni][q];
                }
            }
    }
}

// ---------------------------------------------------------------------------
// GATv2 edge-softmax + aggregate (fp16 xl/xr inputs), 4-edge unroll.
//   out[n,:] = relu( (sum_e alpha_e * xl[src_e]) + bias ) + resid[n,:]
//   W16: also write fp16 copy of out (next layer's GEMM input).
// ---------------------------------------------------------------------------
template<int H, bool W16>
__global__ __launch_bounds__(256) void gat_agg_kernel(const _Float16* __restrict__ xl,
                                                      const _Float16* __restrict__ xr,
                                                      const float* __restrict__ att,
                                                      const float* __restrict__ bias,
                                                      const float* __restrict__ resid,
                                                      const int* __restrict__ offs,
                                                      const int* __restrict__ esrc,
                                                      float* __restrict__ out,
                                                      _Float16* __restrict__ out16) {
    int wid = threadIdx.x >> 6;
    int lane = threadIdx.x & 63;
    int node = blockIdx.x * 4 + wid;

    auto ld4 = [&](const _Float16* p, int n) -> float4 {
        h4 v = *(const h4*)(p + ((size_t)n << 8) + (lane << 2));
        return make_float4((float)v[0], (float)v[1], (float)v[2], (float)v[3]);
    };

    float4 xrv = ld4(xr, node);
    float4 av = ((const float4*)att)[lane];

    float m = -1e30f, s = 0.f;
    float4 acc = make_float4(0.f, 0.f, 0.f, 0.f);

    auto logit = [&](const float4& xlv) -> float {
        float ex = xlv.x + xrv.x; ex = ex > 0.f ? ex : NEG * ex;
        float ey = xlv.y + xrv.y; ey = ey > 0.f ? ey : NEG * ey;
        float ez = xlv.z + xrv.z; ez = ez > 0.f ? ez : NEG * ez;
        float ew = xlv.w + xrv.w; ew = ew > 0.f ? ew : NEG * ew;
        float lp = ex * av.x + ey * av.y + ez * av.z + ew * av.w;
        lp += __shfl_xor(lp, 1);
        lp += __shfl_xor(lp, 2);
        lp += __shfl_xor(lp, 4);
        lp += __shfl_xor(lp, 8);
        if constexpr (H == 1) {
            lp += __shfl_xor(lp, 16);
            lp += __shfl_xor(lp, 32);
        }
        return lp;
    };

    auto single = [&](int src) {
        float4 xlv = ld4(xl, src);
        float lp = logit(xlv);
        float mn = fmaxf(m, lp);
        float c = __expf(m - mn);
        float p = __expf(lp - mn);
        s = s * c + p;
        acc.x = acc.x * c + p * xlv.x;
        acc.y = acc.y * c + p * xlv.y;
        acc.z = acc.z * c + p * xlv.z;
        acc.w = acc.w * c + p * xlv.w;
        m = mn;
    };

    single(node);                             // self-loop
    int e0 = offs[node], e1 = offs[node + 1];
    int e = e0;
    for (; e + 4 <= e1; e += 4) {
        int s0 = esrc[e], s1 = esrc[e + 1], s2 = esrc[e + 2], s3 = esrc[e + 3];
        float4 x0 = ld4(xl, s0);
        float4 x1 = ld4(xl, s1);
        float4 x2 = ld4(xl, s2);
        float4 x3 = ld4(xl, s3);
        float lp0 = logit(x0);
        float lp1 = logit(x1);
        float lp2 = logit(x2);
        float lp3 = logit(x3);
        float mn = fmaxf(fmaxf(fmaxf(lp0, lp1), fmaxf(lp2, lp3)), m);
        float c  = __expf(m - mn);
        float p0 = __expf(lp0 - mn);
        float p1 = __expf(lp1 - mn);
        float p2 = __expf(lp2 - mn);
        float p3 = __expf(lp3 - mn);
        s = s * c + ((p0 + p1) + (p2 + p3));
        acc.x = acc.x * c + ((p0 * x0.x + p1 * x1.x) + (p2 * x2.x + p3 * x3.x));
        acc.y = acc.y * c + ((p0 * x0.y + p1 * x1.y) + (p2 * x2.y + p3 * x3.y));
        acc.z = acc.z * c + ((p0 * x0.z + p1 * x1.z) + (p2 * x2.z + p3 * x3.z));
        acc.w = acc.w * c + ((p0 * x0.w + p1 * x1.w) + (p2 * x2.w + p3 * x3.w));
        m = mn;
    }
    for (; e < e1; ++e) single(esrc[e]);

    float inv = 1.f / s;
    float4 bv = ((const float4*)bias)[lane];
    float4 rv = ((const float4*)resid)[((size_t)node << 6) + lane];
    float4 o;
    o.x = fmaxf(acc.x * inv + bv.x, 0.f) + rv.x;
    o.y = fmaxf(acc.y * inv + bv.y, 0.f) + rv.y;
    o.z = fmaxf(acc.z * inv + bv.z, 0.f) + rv.z;
    o.w = fmaxf(acc.w * inv + bv.w, 0.f) + rv.w;
    ((float4*)out)[((size_t)node << 6) + lane] = o;
    if constexpr (W16) {
        h4 ov;
        ov[0] = (_Float16)o.x; ov[1] = (_Float16)o.y;
        ov[2] = (_Float16)o.z; ov[3] = (_Float16)o.w;
        *(h4*)(out16 + ((size_t)node << 8) + (lane << 2)) = ov;
    }
}

// ---------------------------------------------------------------------------
// Final projection: out[n] = A[n,:64] . w + b   (wave per row)
// ---------------------------------------------------------------------------
__global__ __launch_bounds__(256) void mlp_final_kernel(const float* __restrict__ A,
                                                        const float* __restrict__ w,
                                                        const float* __restrict__ b,
                                                        float* __restrict__ out) {
    int wid = threadIdx.x >> 6;
    int lane = threadIdx.x & 63;
    int node = blockIdx.x * 4 + wid;
    float v = A[((size_t)node << 6) + lane] * w[lane];
    v += __shfl_xor(v, 1);
    v += __shfl_xor(v, 2);
    v += __shfl_xor(v, 4);
    v += __shfl_xor(v, 8);
    v += __shfl_xor(v, 16);
    v += __shfl_xor(v, 32);
    if (lane == 0) out[node] = v + b[0];
}

// ---------------------------------------------------------------------------
extern "C" void kernel_launch(void* const* d_in, const int* in_sizes, int n_in,
                              void* d_out, int out_size, void* d_ws, size_t ws_size,
                              hipStream_t stream) {
    const float* x     = (const float*)d_in[0];
    const int*   ei    = (const int*)d_in[1];
    const float* Win   = (const float*)d_in[2];
    const float* b_in  = (const float*)d_in[3];
    const float* Wskip = (const float*)d_in[4];
    const float* bskip = (const float*)d_in[5];
    const float* Wl1   = (const float*)d_in[6];
    const float* Wr1   = (const float*)d_in[7];
    const float* att1  = (const float*)d_in[8];
    const float* b1    = (const float*)d_in[9];
    const float* Wl2   = (const float*)d_in[10];
    const float* Wr2   = (const float*)d_in[11];
    const float* att2  = (const float*)d_in[12];
    const float* b2    = (const float*)d_in[13];
    const float* Wl3   = (const float*)d_in[14];
    const float* Wr3   = (const float*)d_in[15];
    const float* att3  = (const float*)d_in[16];
    const float* b3    = (const float*)d_in[17];
    const float* Wm1   = (const float*)d_in[18];
    const float* bm1   = (const float*)d_in[19];
    const float* Wm2   = (const float*)d_in[20];
    const float* bm2   = (const float*)d_in[21];
    const float* Wm3   = (const float*)d_in[22];
    const float* bm3   = (const float*)d_in[23];

    // ---- workspace layout ----
    char* p = (char*)d_ws;
    auto alloc = [&](size_t bytes) { char* r = p; p += (bytes + 255) & ~(size_t)255; return r; };
    const size_t NN = N_NODES;
    float*    tA   = (float*)alloc(NN * 64 * 4);
    float*    tB   = (float*)alloc(NN * 64 * 4);
    float*    skip = (float*)alloc(NN * 256 * 4);   // also reused as out2
    float*    out1 = (float*)alloc(NN * 256 * 4);
    _Float16* o116 = (_Float16*)alloc(NN * 256 * 2);
    _Float16* o216 = (_Float16*)alloc(NN * 256 * 2);
    float*    out3 = (float*)o116;                  // aliases o116+o216 (dead by gat3)
    _Float16* h16  = (_Float16*)alloc(NN * 64 * 2);
    _Float16* xl16 = (_Float16*)alloc(NN * 256 * 2);
    _Float16* xr16 = (_Float16*)alloc(NN * 256 * 2);
    _Float16* Wp1  = (_Float16*)alloc((size_t)64 * 768 * 2);
    _Float16* Wp2  = (_Float16*)alloc((size_t)256 * 512 * 2);
    _Float16* Wp3  = (_Float16*)alloc((size_t)256 * 512 * 2);
    int* cnt    = (int*)alloc(N_NODES * 4);
    int* offs   = (int*)alloc((N_NODES + 1) * 4);
    int* cursor = (int*)alloc(N_NODES * 4);
    int* esrc   = (int*)alloc(E_EDGES * 4);

    const int* src = ei;
    const int* dst = ei + E_EDGES;

    // ---- CSR build ----
    hipMemsetAsync(cnt, 0, N_NODES * sizeof(int), stream);
    hist_kernel<<<E_EDGES / 256, 256, 0, stream>>>(dst, cnt);
    csr_scan_kernel<<<1, 256, 0, stream>>>(cnt, offs, cursor);
    scatter_kernel<<<E_EDGES / 256, 256, 0, stream>>>(src, dst, cursor, esrc);

    // ---- pack weights to fp16 [k/8][NT][8] ----
    int pg = (64 * 256 + 255) / 256;
    pack_w_kernel<<<pg, 256, 0, stream>>>(Wl1, Wp1, 64, 256, 768, 0);
    pack_w_kernel<<<pg, 256, 0, stream>>>(Wr1, Wp1, 64, 256, 768, 256);
    pack_w_kernel<<<pg, 256, 0, stream>>>(Wskip, Wp1, 64, 256, 768, 512);
    int pg2 = (256 * 256 + 255) / 256;
    pack_w_kernel<<<pg2, 256, 0, stream>>>(Wl2, Wp2, 256, 256, 512, 0);
    pack_w_kernel<<<pg2, 256, 0, stream>>>(Wr2, Wp2, 256, 256, 512, 256);
    pack_w_kernel<<<pg2, 256, 0, stream>>>(Wl3, Wp3, 256, 256, 512, 0);
    pack_w_kernel<<<pg2, 256, 0, stream>>>(Wr3, Wp3, 256, 256, 512, 256);

    // ---- input proj: h16 = fp16(relu(x @ Win + b_in)) ----
    gemm_kernel<true, true, true><<<dim3(256, 1), 256, 0, stream>>>(x, Win, b_in, h16, FIN, DIM);

    // ---- conv1: xl|xr|skip in one MFMA GEMM ----
    mfma_gemm_kernel<64><<<dim3(128, 6), 256, 0, stream>>>(h16, Wp1, 768, xl16, xr16, skip, bskip);
    gat_agg_kernel<4, true><<<N_NODES / 4, 256, 0, stream>>>(xl16, xr16, att1, b1, skip, offs, esrc, out1, o116);

    // ---- conv2 ----
    mfma_gemm_kernel<256><<<dim3(128, 4), 256, 0, stream>>>(o116, Wp2, 512, xl16, xr16, nullptr, nullptr);
    gat_agg_kernel<1, true><<<N_NODES / 4, 256, 0, stream>>>(xl16, xr16, att2, b2, out1, offs, esrc, skip /*out2*/, o216);

    // ---- conv3 ----
    mfma_gemm_kernel<256><<<dim3(128, 4), 256, 0, stream>>>(o216, Wp3, 512, xl16, xr16, nullptr, nullptr);
    gat_agg_kernel<1, false><<<N_NODES / 4, 256, 0, stream>>>(xl16, xr16, att3, b3, skip /*out2*/, offs, esrc, out3, nullptr);

    // ---- MLP head (fp32) ----
    gemm_kernel<true, true, false><<<dim3(256, 1), 256, 0, stream>>>(out3, Wm1, bm1, tA, HID, DIM);
    gemm_kernel<true, true, false><<<dim3(256, 1), 256, 0, stream>>>(tA, Wm2, bm2, tB, DIM, DIM);
    mlp_final_kernel<<<N_NODES / 4, 256, 0, stream>>>(tB, Wm3, bm3, (float*)d_out);
}

// Round 4
// 228.001 us; speedup vs baseline: 1.7439x; 1.0460x over previous
//
#include <hip/hip_runtime.h>
#include <cstdint>
#include <cstddef>

#define N_NODES 16384
#define E_EDGES 262144
#define FIN     128
#define DIM     64
#define HID     256
#define NEG     0.2f

typedef _Float16 h8 __attribute__((ext_vector_type(8)));
typedef _Float16 h4 __attribute__((ext_vector_type(4)));
typedef float    f32x4 __attribute__((ext_vector_type(4)));

// ---------------------------------------------------------------------------
// Zero the degree-count array (replaces pathologically slow rocclr fill).
// ---------------------------------------------------------------------------
__global__ __launch_bounds__(256) void zero_cnt_kernel(int4* __restrict__ cnt) {
    cnt[blockIdx.x * 256 + threadIdx.x] = make_int4(0, 0, 0, 0);
}

// ---------------------------------------------------------------------------
// CSR build: histogram -> scan -> scatter
// ---------------------------------------------------------------------------
__global__ __launch_bounds__(256) void hist_kernel(const int* __restrict__ dst,
                                                   int* __restrict__ cnt) {
    int i = blockIdx.x * 256 + threadIdx.x;
    if (i < E_EDGES) atomicAdd(&cnt[dst[i]], 1);
}

__global__ __launch_bounds__(256) void csr_scan_kernel(const int* __restrict__ cnt,
                                                       int* __restrict__ offs,
                                                       int* __restrict__ cursor) {
    __shared__ int bs[256];
    __shared__ int psum[257];
    int tid = threadIdx.x;
    int base = tid * 64;
    int s = 0;
    for (int i = 0; i < 64; ++i) s += cnt[base + i];
    bs[tid] = s;
    __syncthreads();
    if (tid == 0) {
        int r = 0;
        for (int i = 0; i < 256; ++i) { psum[i] = r; r += bs[i]; }
        psum[256] = r;
    }
    __syncthreads();
    int run = psum[tid];
    for (int i = 0; i < 64; ++i) {
        int c = cnt[base + i];
        offs[base + i] = run;
        cursor[base + i] = run;
        run += c;
    }
    if (tid == 255) offs[N_NODES] = run;
}

__global__ __launch_bounds__(256) void scatter_kernel(const int* __restrict__ src,
                                                      const int* __restrict__ dst,
                                                      int* __restrict__ cursor,
                                                      int* __restrict__ esrc) {
    int i = blockIdx.x * 256 + threadIdx.x;
    if (i < E_EDGES) {
        int p = atomicAdd(&cursor[dst[i]], 1);
        esrc[p] = src[i];
    }
}

// ---------------------------------------------------------------------------
// Multi-job weight pack: fp32 W[Ksrc][Nsrc] -> fp16 Wp[k>>3][NT][8] @ colOff.
// One launch packs all 9 weights (blockIdx.y selects the job).
// ---------------------------------------------------------------------------
struct PackJob { const float* W; _Float16* dst; int Ksrc, Nsrc, NT, colOff; };
struct PackJobs { PackJob j[9]; };

__global__ __launch_bounds__(256) void pack_all_kernel(PackJobs jobs) {
    PackJob jb = jobs.j[blockIdx.y];
    int i = blockIdx.x * 256 + threadIdx.x;
    if (i < jb.Ksrc * jb.Nsrc) {
        int k = i / jb.Nsrc, n = i % jb.Nsrc;
        jb.dst[((size_t)(k >> 3) * jb.NT + jb.colOff + n) * 8 + (k & 7)] = (_Float16)jb.W[i];
    }
}

// ---------------------------------------------------------------------------
// Cast fp32 -> fp16 (float4 granularity).
// ---------------------------------------------------------------------------
__global__ __launch_bounds__(256) void cast16_kernel(const float* __restrict__ x,
                                                     _Float16* __restrict__ x16) {
    int i = blockIdx.x * 256 + threadIdx.x;
    float4 v = ((const float4*)x)[i];
    h4 o; o[0] = (_Float16)v.x; o[1] = (_Float16)v.y;
    o[2] = (_Float16)v.z; o[3] = (_Float16)v.w;
    ((h4*)x16)[i] = o;
}

// ---------------------------------------------------------------------------
// fp16 MFMA GEMM, M(out)=64 variant: out = act(A[N][K] @ Wp + bias)
//   Wp packed [K/8][64][8]. Block = 4 waves, each wave 64 rows x 64 cols.
// MFMA f32_16x16x32_f16: A row=l&15,k=(l>>4)*8+j; B col=l&15; C col=l&15,
// row=(l>>4)*4+q.
// ---------------------------------------------------------------------------
template<int K, bool RELU, bool O16>
__global__ __launch_bounds__(256) void mfma_nt64_kernel(const _Float16* __restrict__ A,
                                                        const _Float16* __restrict__ Wp,
                                                        const float* __restrict__ bias,
                                                        void* __restrict__ outv) {
    int tid = threadIdx.x;
    int lane = tid & 63, wid = tid >> 6;
    int rowBase = blockIdx.x * 256 + wid * 64;
    int l15 = lane & 15, l4 = lane >> 4;

    f32x4 acc[4][4] = {};
#pragma unroll
    for (int ks = 0; ks < K / 32; ++ks) {
        h8 af[4], bf[4];
#pragma unroll
        for (int mi = 0; mi < 4; ++mi)
            af[mi] = *(const h8*)(A + (size_t)(rowBase + mi * 16 + l15) * K + ks * 32 + l4 * 8);
#pragma unroll
        for (int ni = 0; ni < 4; ++ni)
            bf[ni] = *(const h8*)(Wp + ((size_t)(ks * 4 + l4) * 64 + ni * 16 + l15) * 8);
#pragma unroll
        for (int mi = 0; mi < 4; ++mi)
#pragma unroll
            for (int ni = 0; ni < 4; ++ni)
                acc[mi][ni] = __builtin_amdgcn_mfma_f32_16x16x32_f16(af[mi], bf[ni], acc[mi][ni], 0, 0, 0);
    }
#pragma unroll
    for (int mi = 0; mi < 4; ++mi)
#pragma unroll
        for (int ni = 0; ni < 4; ++ni) {
            int c = ni * 16 + l15;
            float bv = bias[c];
#pragma unroll
            for (int q = 0; q < 4; ++q) {
                int r = rowBase + mi * 16 + l4 * 4 + q;
                float v = acc[mi][ni][q] + bv;
                if (RELU) v = fmaxf(v, 0.f);
                if constexpr (O16) ((_Float16*)outv)[(size_t)r * 64 + c] = (_Float16)v;
                else               ((float*)outv)[(size_t)r * 64 + c] = v;
            }
        }
}

// ---------------------------------------------------------------------------
// fp16 MFMA GEMM, no-LDS direct-fragment form (wide: NT packed cols).
//   Tile 128 rows x 128 packed cols (4 waves 2x2). Packed cols segment into
//   256-wide outputs: seg0->o16a, seg1->o16b, seg2->o32 (+bias fp32).
// ---------------------------------------------------------------------------
template<int K>
__global__ __launch_bounds__(256) void mfma_gemm_kernel(const _Float16* __restrict__ A,
                                                        const _Float16* __restrict__ Wp,
                                                        int NT,
                                                        _Float16* __restrict__ o16a,
                                                        _Float16* __restrict__ o16b,
                                                        float* __restrict__ o32,
                                                        const float* __restrict__ bias) {
    int tid = threadIdx.x;
    int lane = tid & 63, wid = tid >> 6;
    int wm = wid >> 1, wn = wid & 1;
    int rowBase = blockIdx.x * 128 + wm * 64;
    int colBase = blockIdx.y * 128 + wn * 64;
    int l15 = lane & 15, l4 = lane >> 4;

    f32x4 acc[4][4] = {};
#pragma unroll
    for (int ks = 0; ks < K / 32; ++ks) {
        h8 af[4], bf[4];
#pragma unroll
        for (int mi = 0; mi < 4; ++mi)
            af[mi] = *(const h8*)(A + (size_t)(rowBase + mi * 16 + l15) * K + ks * 32 + l4 * 8);
#pragma unroll
        for (int ni = 0; ni < 4; ++ni)
            bf[ni] = *(const h8*)(Wp + ((size_t)(ks * 4 + l4) * NT + colBase + ni * 16 + l15) * 8);
#pragma unroll
        for (int mi = 0; mi < 4; ++mi)
#pragma unroll
            for (int ni = 0; ni < 4; ++ni)
                acc[mi][ni] = __builtin_amdgcn_mfma_f32_16x16x32_f16(af[mi], bf[ni], acc[mi][ni], 0, 0, 0);
    }

    int seg = colBase >> 8;
    int cbase = colBase & 255;
    if (o32 != nullptr && seg == 2) {
#pragma unroll
        for (int mi = 0; mi < 4; ++mi)
#pragma unroll
            for (int ni = 0; ni < 4; ++ni) {
                int c = cbase + ni * 16 + l15;
                float bv = bias[c];
#pragma unroll
                for (int q = 0; q < 4; ++q) {
                    int r = rowBase + mi * 16 + l4 * 4 + q;
                    o32[(size_t)r * 256 + c] = acc[mi][ni][q] + bv;
                }
            }
    } else {
        _Float16* o = (seg == 0) ? o16a : o16b;
#pragma unroll
        for (int mi = 0; mi < 4; ++mi)
#pragma unroll
            for (int ni = 0; ni < 4; ++ni) {
                int c = cbase + ni * 16 + l15;
#pragma unroll
                for (int q = 0; q < 4; ++q) {
                    int r = rowBase + mi * 16 + l4 * 4 + q;
                    o[(size_t)r * 256 + c] = (_Float16)acc[mi][ni][q];
                }
            }
    }
}

// ---------------------------------------------------------------------------
// GATv2 edge-softmax + aggregate (fp16 xl/xr), 4-edge unroll.
//   out[n,:] = relu( (sum_e alpha_e * xl[src_e]) + bias ) + resid[n,:]
// OMODE: 0 = fp32 out only, 1 = fp32 + fp16 outs, 2 = fp16 out only.
// ---------------------------------------------------------------------------
template<int H, int OMODE>
__global__ __launch_bounds__(256) void gat_agg_kernel(const _Float16* __restrict__ xl,
                                                      const _Float16* __restrict__ xr,
                                                      const float* __restrict__ att,
                                                      const float* __restrict__ bias,
                                                      const float* __restrict__ resid,
                                                      const int* __restrict__ offs,
                                                      const int* __restrict__ esrc,
                                                      float* __restrict__ out,
                                                      _Float16* __restrict__ out16) {
    int wid = threadIdx.x >> 6;
    int lane = threadIdx.x & 63;
    int node = blockIdx.x * 4 + wid;

    auto ld4 = [&](const _Float16* p, int n) -> float4 {
        h4 v = *(const h4*)(p + ((size_t)n << 8) + (lane << 2));
        return make_float4((float)v[0], (float)v[1], (float)v[2], (float)v[3]);
    };

    float4 xrv = ld4(xr, node);
    float4 av = ((const float4*)att)[lane];

    float m = -1e30f, s = 0.f;
    float4 acc = make_float4(0.f, 0.f, 0.f, 0.f);

    auto logit = [&](const float4& xlv) -> float {
        float ex = xlv.x + xrv.x; ex = ex > 0.f ? ex : NEG * ex;
        float ey = xlv.y + xrv.y; ey = ey > 0.f ? ey : NEG * ey;
        float ez = xlv.z + xrv.z; ez = ez > 0.f ? ez : NEG * ez;
        float ew = xlv.w + xrv.w; ew = ew > 0.f ? ew : NEG * ew;
        float lp = ex * av.x + ey * av.y + ez * av.z + ew * av.w;
        lp += __shfl_xor(lp, 1);
        lp += __shfl_xor(lp, 2);
        lp += __shfl_xor(lp, 4);
        lp += __shfl_xor(lp, 8);
        if constexpr (H == 1) {
            lp += __shfl_xor(lp, 16);
            lp += __shfl_xor(lp, 32);
        }
        return lp;
    };

    auto single = [&](int src) {
        float4 xlv = ld4(xl, src);
        float lp = logit(xlv);
        float mn = fmaxf(m, lp);
        float c = __expf(m - mn);
        float p = __expf(lp - mn);
        s = s * c + p;
        acc.x = acc.x * c + p * xlv.x;
        acc.y = acc.y * c + p * xlv.y;
        acc.z = acc.z * c + p * xlv.z;
        acc.w = acc.w * c + p * xlv.w;
        m = mn;
    };

    single(node);                             // self-loop
    int e0 = offs[node], e1 = offs[node + 1];
    int e = e0;
    for (; e + 4 <= e1; e += 4) {
        int s0 = esrc[e], s1 = esrc[e + 1], s2 = esrc[e + 2], s3 = esrc[e + 3];
        float4 x0 = ld4(xl, s0);
        float4 x1 = ld4(xl, s1);
        float4 x2 = ld4(xl, s2);
        float4 x3 = ld4(xl, s3);
        float lp0 = logit(x0);
        float lp1 = logit(x1);
        float lp2 = logit(x2);
        float lp3 = logit(x3);
        float mn = fmaxf(fmaxf(fmaxf(lp0, lp1), fmaxf(lp2, lp3)), m);
        float c  = __expf(m - mn);
        float p0 = __expf(lp0 - mn);
        float p1 = __expf(lp1 - mn);
        float p2 = __expf(lp2 - mn);
        float p3 = __expf(lp3 - mn);
        s = s * c + ((p0 + p1) + (p2 + p3));
        acc.x = acc.x * c + ((p0 * x0.x + p1 * x1.x) + (p2 * x2.x + p3 * x3.x));
        acc.y = acc.y * c + ((p0 * x0.y + p1 * x1.y) + (p2 * x2.y + p3 * x3.y));
        acc.z = acc.z * c + ((p0 * x0.z + p1 * x1.z) + (p2 * x2.z + p3 * x3.z));
        acc.w = acc.w * c + ((p0 * x0.w + p1 * x1.w) + (p2 * x2.w + p3 * x3.w));
        m = mn;
    }
    for (; e < e1; ++e) single(esrc[e]);

    float inv = 1.f / s;
    float4 bv = ((const float4*)bias)[lane];
    float4 rv = ((const float4*)resid)[((size_t)node << 6) + lane];
    float4 o;
    o.x = fmaxf(acc.x * inv + bv.x, 0.f) + rv.x;
    o.y = fmaxf(acc.y * inv + bv.y, 0.f) + rv.y;
    o.z = fmaxf(acc.z * inv + bv.z, 0.f) + rv.z;
    o.w = fmaxf(acc.w * inv + bv.w, 0.f) + rv.w;
    if constexpr (OMODE != 2)
        ((float4*)out)[((size_t)node << 6) + lane] = o;
    if constexpr (OMODE != 0) {
        h4 ov;
        ov[0] = (_Float16)o.x; ov[1] = (_Float16)o.y;
        ov[2] = (_Float16)o.z; ov[3] = (_Float16)o.w;
        *(h4*)(out16 + ((size_t)node << 8) + (lane << 2)) = ov;
    }
}

// ---------------------------------------------------------------------------
// Fused MLP tail: out[n] = relu(tA[n,:]@Wm2 + bm2) @ Wm3 + bm3
// One wave per node (8 nodes/wave sequentially); Wm2 staged in LDS [64][65].
// ---------------------------------------------------------------------------
__global__ __launch_bounds__(256) void mlp23_kernel(const float* __restrict__ tA,
                                                    const float* __restrict__ Wm2,
                                                    const float* __restrict__ bm2,
                                                    const float* __restrict__ Wm3,
                                                    const float* __restrict__ bm3,
                                                    float* __restrict__ out) {
    __shared__ float W2s[64][65];
    __shared__ float w3s[64];
    int tid = threadIdx.x;
    for (int i = tid; i < 4096; i += 256) W2s[i >> 6][i & 63] = Wm2[i];
    if (tid < 64) w3s[tid] = Wm3[tid];
    __syncthreads();
    int wid = tid >> 6, lane = tid & 63;
    float b2 = bm2[lane];
    float b3 = bm3[0];
#pragma unroll 1
    for (int i = 0; i < 8; ++i) {
        int node = blockIdx.x * 32 + wid * 8 + i;
        float a = tA[((size_t)node << 6) + lane];
        float accv = 0.f;
#pragma unroll
        for (int k = 0; k < 64; ++k) accv += __shfl(a, k) * W2s[k][lane];
        float o = fmaxf(accv + b2, 0.f) * w3s[lane];
        o += __shfl_xor(o, 1);
        o += __shfl_xor(o, 2);
        o += __shfl_xor(o, 4);
        o += __shfl_xor(o, 8);
        o += __shfl_xor(o, 16);
        o += __shfl_xor(o, 32);
        if (lane == 0) out[node] = o + b3;
    }
}

// ---------------------------------------------------------------------------
extern "C" void kernel_launch(void* const* d_in, const int* in_sizes, int n_in,
                              void* d_out, int out_size, void* d_ws, size_t ws_size,
                              hipStream_t stream) {
    const float* x     = (const float*)d_in[0];
    const int*   ei    = (const int*)d_in[1];
    const float* Win   = (const float*)d_in[2];
    const float* b_in  = (const float*)d_in[3];
    const float* Wskip = (const float*)d_in[4];
    const float* bskip = (const float*)d_in[5];
    const float* Wl1   = (const float*)d_in[6];
    const float* Wr1   = (const float*)d_in[7];
    const float* att1  = (const float*)d_in[8];
    const float* b1    = (const float*)d_in[9];
    const float* Wl2   = (const float*)d_in[10];
    const float* Wr2   = (const float*)d_in[11];
    const float* att2  = (const float*)d_in[12];
    const float* b2    = (const float*)d_in[13];
    const float* Wl3   = (const float*)d_in[14];
    const float* Wr3   = (const float*)d_in[15];
    const float* att3  = (const float*)d_in[16];
    const float* b3    = (const float*)d_in[17];
    const float* Wm1   = (const float*)d_in[18];
    const float* bm1   = (const float*)d_in[19];
    const float* Wm2   = (const float*)d_in[20];
    const float* bm2   = (const float*)d_in[21];
    const float* Wm3   = (const float*)d_in[22];
    const float* bm3   = (const float*)d_in[23];

    // ---- workspace layout ----
    char* p = (char*)d_ws;
    auto alloc = [&](size_t bytes) { char* r = p; p += (bytes + 255) & ~(size_t)255; return r; };
    const size_t NN = N_NODES;
    float*    tA   = (float*)alloc(NN * 64 * 4);
    float*    skip = (float*)alloc(NN * 256 * 4);   // also out2
    float*    out1 = (float*)alloc(NN * 256 * 4);
    _Float16* o116 = (_Float16*)alloc(NN * 256 * 2);
    _Float16* o216 = (_Float16*)alloc(NN * 256 * 2);
    _Float16* o316 = o116;                          // o116 dead by gat3
    _Float16* h16  = (_Float16*)alloc(NN * 64 * 2);
    _Float16* x16  = (_Float16*)alloc(NN * FIN * 2);
    _Float16* xl16 = (_Float16*)alloc(NN * 256 * 2);
    _Float16* xr16 = (_Float16*)alloc(NN * 256 * 2);
    _Float16* Wp1  = (_Float16*)alloc((size_t)64 * 768 * 2);
    _Float16* Wp2  = (_Float16*)alloc((size_t)256 * 512 * 2);
    _Float16* Wp3  = (_Float16*)alloc((size_t)256 * 512 * 2);
    _Float16* Winp = (_Float16*)alloc((size_t)128 * 64 * 2);
    _Float16* Wm1p = (_Float16*)alloc((size_t)256 * 64 * 2);
    int* cnt    = (int*)alloc(N_NODES * 4);
    int* offs   = (int*)alloc((N_NODES + 1) * 4);
    int* cursor = (int*)alloc(N_NODES * 4);
    int* esrc   = (int*)alloc(E_EDGES * 4);

    const int* src = ei;
    const int* dst = ei + E_EDGES;

    // ---- CSR build ----
    zero_cnt_kernel<<<N_NODES / 1024, 256, 0, stream>>>((int4*)cnt);
    hist_kernel<<<E_EDGES / 256, 256, 0, stream>>>(dst, cnt);
    csr_scan_kernel<<<1, 256, 0, stream>>>(cnt, offs, cursor);
    scatter_kernel<<<E_EDGES / 256, 256, 0, stream>>>(src, dst, cursor, esrc);

    // ---- pack all weights (one launch) ----
    PackJobs jobs = {{
        { Wl1,   Wp1,  64,  256, 768, 0   },
        { Wr1,   Wp1,  64,  256, 768, 256 },
        { Wskip, Wp1,  64,  256, 768, 512 },
        { Wl2,   Wp2,  256, 256, 512, 0   },
        { Wr2,   Wp2,  256, 256, 512, 256 },
        { Wl3,   Wp3,  256, 256, 512, 0   },
        { Wr3,   Wp3,  256, 256, 512, 256 },
        { Win,   Winp, 128, 64,  64,  0   },
        { Wm1,   Wm1p, 256, 64,  64,  0   },
    }};
    pack_all_kernel<<<dim3(256, 9), 256, 0, stream>>>(jobs);

    // ---- input proj: h16 = fp16(relu(x @ Win + b_in)) via MFMA ----
    cast16_kernel<<<(N_NODES * FIN / 4) / 256, 256, 0, stream>>>(x, x16);
    mfma_nt64_kernel<128, true, true><<<N_NODES / 256, 256, 0, stream>>>(x16, Winp, b_in, h16);

    // ---- conv1: xl|xr|skip in one MFMA GEMM ----
    mfma_gemm_kernel<64><<<dim3(128, 6), 256, 0, stream>>>(h16, Wp1, 768, xl16, xr16, skip, bskip);
    gat_agg_kernel<4, 1><<<N_NODES / 4, 256, 0, stream>>>(xl16, xr16, att1, b1, skip, offs, esrc, out1, o116);

    // ---- conv2 ----
    mfma_gemm_kernel<256><<<dim3(128, 4), 256, 0, stream>>>(o116, Wp2, 512, xl16, xr16, nullptr, nullptr);
    gat_agg_kernel<1, 1><<<N_NODES / 4, 256, 0, stream>>>(xl16, xr16, att2, b2, out1, offs, esrc, skip /*out2*/, o216);

    // ---- conv3 (fp16-only output -> o316) ----
    mfma_gemm_kernel<256><<<dim3(128, 4), 256, 0, stream>>>(o216, Wp3, 512, xl16, xr16, nullptr, nullptr);
    gat_agg_kernel<1, 2><<<N_NODES / 4, 256, 0, stream>>>(xl16, xr16, att3, b3, skip /*out2*/, offs, esrc, nullptr, o316);

    // ---- MLP head: tA = relu(o316 @ Wm1 + bm1) via MFMA, then fused 2+3 ----
    mfma_nt64_kernel<256, true, false><<<N_NODES / 256, 256, 0, stream>>>(o316, Wm1p, bm1, tA);
    mlp23_kernel<<<N_NODES / 32, 256, 0, stream>>>(tA, Wm2, bm2, Wm3, bm3, (float*)d_out);
}

// Round 5
// 225.481 us; speedup vs baseline: 1.7634x; 1.0112x over previous
//
#include <hip/hip_runtime.h>
#include <cstdint>
#include <cstddef>

#define N_NODES 16384
#define E_EDGES 262144
#define FIN     128
#define DIM     64
#define HID     256
#define NEG     0.2f

typedef _Float16 h8 __attribute__((ext_vector_type(8)));
typedef _Float16 h4 __attribute__((ext_vector_type(4)));
typedef float    f32x4 __attribute__((ext_vector_type(4)));

// ---------------------------------------------------------------------------
// Zero the degree-count array (rocclr fill is pathologically slow at 64KB).
// ---------------------------------------------------------------------------
__global__ __launch_bounds__(256) void zero_cnt_kernel(int4* __restrict__ cnt) {
    cnt[blockIdx.x * 256 + threadIdx.x] = make_int4(0, 0, 0, 0);
}

// ---------------------------------------------------------------------------
// CSR build: histogram -> scan -> scatter
// ---------------------------------------------------------------------------
__global__ __launch_bounds__(256) void hist_kernel(const int* __restrict__ dst,
                                                   int* __restrict__ cnt) {
    int i = blockIdx.x * 256 + threadIdx.x;
    if (i < E_EDGES) atomicAdd(&cnt[dst[i]], 1);
}

__global__ __launch_bounds__(256) void csr_scan_kernel(const int* __restrict__ cnt,
                                                       int* __restrict__ offs,
                                                       int* __restrict__ cursor) {
    __shared__ int bs[256];
    __shared__ int psum[257];
    int tid = threadIdx.x;
    int base = tid * 64;
    int s = 0;
    for (int i = 0; i < 64; ++i) s += cnt[base + i];
    bs[tid] = s;
    __syncthreads();
    if (tid == 0) {
        int r = 0;
        for (int i = 0; i < 256; ++i) { psum[i] = r; r += bs[i]; }
        psum[256] = r;
    }
    __syncthreads();
    int run = psum[tid];
    for (int i = 0; i < 64; ++i) {
        int c = cnt[base + i];
        offs[base + i] = run;
        cursor[base + i] = run;
        run += c;
    }
    if (tid == 255) offs[N_NODES] = run;
}

__global__ __launch_bounds__(256) void scatter_kernel(const int* __restrict__ src,
                                                      const int* __restrict__ dst,
                                                      int* __restrict__ cursor,
                                                      int* __restrict__ esrc) {
    int i = blockIdx.x * 256 + threadIdx.x;
    if (i < E_EDGES) {
        int p = atomicAdd(&cursor[dst[i]], 1);
        esrc[p] = src[i];
    }
}

// ---------------------------------------------------------------------------
// Multi-job weight pack: fp32 W[Ksrc][Nsrc] -> fp16 Wp[k>>3][NT][8] @ colOff.
// ---------------------------------------------------------------------------
struct PackJob { const float* W; _Float16* dst; int Ksrc, Nsrc, NT, colOff; };
struct PackJobs { PackJob j[10]; };

__global__ __launch_bounds__(256) void pack_all_kernel(PackJobs jobs) {
    PackJob jb = jobs.j[blockIdx.y];
    int i = blockIdx.x * 256 + threadIdx.x;
    if (i < jb.Ksrc * jb.Nsrc) {
        int k = i / jb.Nsrc, n = i % jb.Nsrc;
        jb.dst[((size_t)(k >> 3) * jb.NT + jb.colOff + n) * 8 + (k & 7)] = (_Float16)jb.W[i];
    }
}

// ---------------------------------------------------------------------------
// MFMA GEMM, 64-wide output, 1 wave/block (64 rows): out = act(A@Wp + bias)
// IN32: A is fp32, converted in-register (fuses the cast).
// MFMA f32_16x16x32_f16: A row=l&15,k=(l>>4)*8+j; B col=l&15; C col=l&15,
// row=(l>>4)*4+q.
// ---------------------------------------------------------------------------
template<int K, bool RELU, bool O16, bool IN32>
__global__ __launch_bounds__(64) void mfma_n64_kernel(const void* __restrict__ Av,
                                                      const _Float16* __restrict__ Wp,
                                                      const float* __restrict__ bias,
                                                      void* __restrict__ outv) {
    int lane = threadIdx.x;
    int rowBase = blockIdx.x * 64;
    int l15 = lane & 15, l4 = lane >> 4;

    f32x4 acc[4][4] = {};
#pragma unroll
    for (int ks = 0; ks < K / 32; ++ks) {
        h8 af[4], bf[4];
#pragma unroll
        for (int mi = 0; mi < 4; ++mi) {
            if constexpr (IN32) {
                const float* ap = (const float*)Av + (size_t)(rowBase + mi * 16 + l15) * K + ks * 32 + l4 * 8;
                float4 a0 = *(const float4*)ap;
                float4 a1 = *(const float4*)(ap + 4);
                h8 v;
                v[0] = (_Float16)a0.x; v[1] = (_Float16)a0.y;
                v[2] = (_Float16)a0.z; v[3] = (_Float16)a0.w;
                v[4] = (_Float16)a1.x; v[5] = (_Float16)a1.y;
                v[6] = (_Float16)a1.z; v[7] = (_Float16)a1.w;
                af[mi] = v;
            } else {
                af[mi] = *(const h8*)((const _Float16*)Av + (size_t)(rowBase + mi * 16 + l15) * K + ks * 32 + l4 * 8);
            }
        }
#pragma unroll
        for (int ni = 0; ni < 4; ++ni)
            bf[ni] = *(const h8*)(Wp + ((size_t)(ks * 4 + l4) * 64 + ni * 16 + l15) * 8);
#pragma unroll
        for (int mi = 0; mi < 4; ++mi)
#pragma unroll
            for (int ni = 0; ni < 4; ++ni)
                acc[mi][ni] = __builtin_amdgcn_mfma_f32_16x16x32_f16(af[mi], bf[ni], acc[mi][ni], 0, 0, 0);
    }
#pragma unroll
    for (int mi = 0; mi < 4; ++mi)
#pragma unroll
        for (int ni = 0; ni < 4; ++ni) {
            int c = ni * 16 + l15;
            float bv = bias[c];
#pragma unroll
            for (int q = 0; q < 4; ++q) {
                int r = rowBase + mi * 16 + l4 * 4 + q;
                float v = acc[mi][ni][q] + bv;
                if (RELU) v = fmaxf(v, 0.f);
                if constexpr (O16) ((_Float16*)outv)[(size_t)r * 64 + c] = (_Float16)v;
                else               ((float*)outv)[(size_t)r * 64 + c] = v;
            }
        }
}

// ---------------------------------------------------------------------------
// fp16 MFMA GEMM, no-LDS direct-fragment, wide (NT packed cols).
//   Tile 128 rows x 128 packed cols (4 waves 2x2). Col segments of 256 map to
//   o16a / o16b / o32(+bias fp32).
// ---------------------------------------------------------------------------
template<int K>
__global__ __launch_bounds__(256) void mfma_gemm_kernel(const _Float16* __restrict__ A,
                                                        const _Float16* __restrict__ Wp,
                                                        int NT,
                                                        _Float16* __restrict__ o16a,
                                                        _Float16* __restrict__ o16b,
                                                        float* __restrict__ o32,
                                                        const float* __restrict__ bias) {
    int tid = threadIdx.x;
    int lane = tid & 63, wid = tid >> 6;
    int wm = wid >> 1, wn = wid & 1;
    int rowBase = blockIdx.x * 128 + wm * 64;
    int colBase = blockIdx.y * 128 + wn * 64;
    int l15 = lane & 15, l4 = lane >> 4;

    f32x4 acc[4][4] = {};
#pragma unroll
    for (int ks = 0; ks < K / 32; ++ks) {
        h8 af[4], bf[4];
#pragma unroll
        for (int mi = 0; mi < 4; ++mi)
            af[mi] = *(const h8*)(A + (size_t)(rowBase + mi * 16 + l15) * K + ks * 32 + l4 * 8);
#pragma unroll
        for (int ni = 0; ni < 4; ++ni)
            bf[ni] = *(const h8*)(Wp + ((size_t)(ks * 4 + l4) * NT + colBase + ni * 16 + l15) * 8);
#pragma unroll
        for (int mi = 0; mi < 4; ++mi)
#pragma unroll
            for (int ni = 0; ni < 4; ++ni)
                acc[mi][ni] = __builtin_amdgcn_mfma_f32_16x16x32_f16(af[mi], bf[ni], acc[mi][ni], 0, 0, 0);
    }

    int seg = colBase >> 8;
    int cbase = colBase & 255;
    if (o32 != nullptr && seg == 2) {
#pragma unroll
        for (int mi = 0; mi < 4; ++mi)
#pragma unroll
            for (int ni = 0; ni < 4; ++ni) {
                int c = cbase + ni * 16 + l15;
                float bv = bias[c];
#pragma unroll
                for (int q = 0; q < 4; ++q) {
                    int r = rowBase + mi * 16 + l4 * 4 + q;
                    o32[(size_t)r * 256 + c] = acc[mi][ni][q] + bv;
                }
            }
    } else {
        _Float16* o = (seg == 0) ? o16a : o16b;
#pragma unroll
        for (int mi = 0; mi < 4; ++mi)
#pragma unroll
            for (int ni = 0; ni < 4; ++ni) {
                int c = cbase + ni * 16 + l15;
#pragma unroll
                for (int q = 0; q < 4; ++q) {
                    int r = rowBase + mi * 16 + l4 * 4 + q;
                    o[(size_t)r * 256 + c] = (_Float16)acc[mi][ni][q];
                }
            }
    }
}

// ---------------------------------------------------------------------------
// GATv2 edge-softmax + aggregate (fp16 xl/xr), 8-edge unrolled online softmax.
//   out[n,:] = relu( (sum_e alpha_e * xl[src_e]) + bias ) + resid[n,:]
// OMODE: 0 = fp32 out only, 1 = fp32 + fp16, 2 = fp16 only.
// ---------------------------------------------------------------------------
template<int H, int OMODE>
__global__ __launch_bounds__(256) void gat_agg_kernel(const _Float16* __restrict__ xl,
                                                      const _Float16* __restrict__ xr,
                                                      const float* __restrict__ att,
                                                      const float* __restrict__ bias,
                                                      const float* __restrict__ resid,
                                                      const int* __restrict__ offs,
                                                      const int* __restrict__ esrc,
                                                      float* __restrict__ out,
                                                      _Float16* __restrict__ out16) {
    int wid = threadIdx.x >> 6;
    int lane = threadIdx.x & 63;
    int node = blockIdx.x * 4 + wid;

    auto ld4 = [&](const _Float16* p, int n) -> float4 {
        h4 v = *(const h4*)(p + ((size_t)n << 8) + (lane << 2));
        return make_float4((float)v[0], (float)v[1], (float)v[2], (float)v[3]);
    };

    float4 xrv = ld4(xr, node);
    float4 av = ((const float4*)att)[lane];

    float m = -1e30f, s = 0.f;
    float4 acc = make_float4(0.f, 0.f, 0.f, 0.f);

    auto logit = [&](const float4& xlv) -> float {
        float ex = xlv.x + xrv.x; ex = ex > 0.f ? ex : NEG * ex;
        float ey = xlv.y + xrv.y; ey = ey > 0.f ? ey : NEG * ey;
        float ez = xlv.z + xrv.z; ez = ez > 0.f ? ez : NEG * ez;
        float ew = xlv.w + xrv.w; ew = ew > 0.f ? ew : NEG * ew;
        float lp = ex * av.x + ey * av.y + ez * av.z + ew * av.w;
        lp += __shfl_xor(lp, 1);
        lp += __shfl_xor(lp, 2);
        lp += __shfl_xor(lp, 4);
        lp += __shfl_xor(lp, 8);
        if constexpr (H == 1) {
            lp += __shfl_xor(lp, 16);
            lp += __shfl_xor(lp, 32);
        }
        return lp;
    };

    auto single = [&](int src) {
        float4 xlv = ld4(xl, src);
        float lp = logit(xlv);
        float mn = fmaxf(m, lp);
        float c = __expf(m - mn);
        float p = __expf(lp - mn);
        s = s * c + p;
        acc.x = acc.x * c + p * xlv.x;
        acc.y = acc.y * c + p * xlv.y;
        acc.z = acc.z * c + p * xlv.z;
        acc.w = acc.w * c + p * xlv.w;
        m = mn;
    };

    single(node);                             // self-loop
    int e0 = offs[node], e1 = offs[node + 1];
    int e = e0;
    for (; e + 8 <= e1; e += 8) {
        float4 xv[8]; float lp[8], pp[8];
#pragma unroll
        for (int j = 0; j < 8; ++j) xv[j] = ld4(xl, esrc[e + j]);
#pragma unroll
        for (int j = 0; j < 8; ++j) lp[j] = logit(xv[j]);
        float mn = m;
#pragma unroll
        for (int j = 0; j < 8; ++j) mn = fmaxf(mn, lp[j]);
        float c = __expf(m - mn);
#pragma unroll
        for (int j = 0; j < 8; ++j) pp[j] = __expf(lp[j] - mn);
        float ps = 0.f;
        float4 pa = make_float4(0.f, 0.f, 0.f, 0.f);
#pragma unroll
        for (int j = 0; j < 8; ++j) {
            ps += pp[j];
            pa.x += pp[j] * xv[j].x;
            pa.y += pp[j] * xv[j].y;
            pa.z += pp[j] * xv[j].z;
            pa.w += pp[j] * xv[j].w;
        }
        s = s * c + ps;
        acc.x = acc.x * c + pa.x;
        acc.y = acc.y * c + pa.y;
        acc.z = acc.z * c + pa.z;
        acc.w = acc.w * c + pa.w;
        m = mn;
    }
    for (; e + 4 <= e1; e += 4) {
        float4 xv[4]; float lp[4], pp[4];
#pragma unroll
        for (int j = 0; j < 4; ++j) xv[j] = ld4(xl, esrc[e + j]);
#pragma unroll
        for (int j = 0; j < 4; ++j) lp[j] = logit(xv[j]);
        float mn = fmaxf(fmaxf(fmaxf(lp[0], lp[1]), fmaxf(lp[2], lp[3])), m);
        float c = __expf(m - mn);
#pragma unroll
        for (int j = 0; j < 4; ++j) pp[j] = __expf(lp[j] - mn);
        s = s * c + ((pp[0] + pp[1]) + (pp[2] + pp[3]));
        acc.x = acc.x * c + ((pp[0] * xv[0].x + pp[1] * xv[1].x) + (pp[2] * xv[2].x + pp[3] * xv[3].x));
        acc.y = acc.y * c + ((pp[0] * xv[0].y + pp[1] * xv[1].y) + (pp[2] * xv[2].y + pp[3] * xv[3].y));
        acc.z = acc.z * c + ((pp[0] * xv[0].z + pp[1] * xv[1].z) + (pp[2] * xv[2].z + pp[3] * xv[3].z));
        acc.w = acc.w * c + ((pp[0] * xv[0].w + pp[1] * xv[1].w) + (pp[2] * xv[2].w + pp[3] * xv[3].w));
        m = mn;
    }
    for (; e < e1; ++e) single(esrc[e]);

    float inv = 1.f / s;
    float4 bv = ((const float4*)bias)[lane];
    float4 rv = ((const float4*)resid)[((size_t)node << 6) + lane];
    float4 o;
    o.x = fmaxf(acc.x * inv + bv.x, 0.f) + rv.x;
    o.y = fmaxf(acc.y * inv + bv.y, 0.f) + rv.y;
    o.z = fmaxf(acc.z * inv + bv.z, 0.f) + rv.z;
    o.w = fmaxf(acc.w * inv + bv.w, 0.f) + rv.w;
    if constexpr (OMODE != 2)
        ((float4*)out)[((size_t)node << 6) + lane] = o;
    if constexpr (OMODE != 0) {
        h4 ov;
        ov[0] = (_Float16)o.x; ov[1] = (_Float16)o.y;
        ov[2] = (_Float16)o.z; ov[3] = (_Float16)o.w;
        *(h4*)(out16 + ((size_t)node << 8) + (lane << 2)) = ov;
    }
}

// ---------------------------------------------------------------------------
// Fused MLP head, 1 wave/block (64 rows):
//   out[n] = relu(relu(o316[n]@Wm1+bm1)@Wm2+bm2) @ Wm3 + bm3
// Phase1 MFMA K=256 -> fp16 LDS (stride 72); Phase2 MFMA K=64; Phase3 dot+shfl.
// Single wave per block => no barriers; LDS is wave-private.
// ---------------------------------------------------------------------------
__global__ __launch_bounds__(64) void mlp_head_kernel(const _Float16* __restrict__ A,
                                                      const _Float16* __restrict__ Wm1p,
                                                      const float* __restrict__ bm1,
                                                      const _Float16* __restrict__ Wm2p,
                                                      const float* __restrict__ bm2,
                                                      const float* __restrict__ Wm3,
                                                      const float* __restrict__ bm3,
                                                      float* __restrict__ out) {
    __shared__ _Float16 t1s[64][72];
    int lane = threadIdx.x;
    int rowBase = blockIdx.x * 64;
    int l15 = lane & 15, l4 = lane >> 4;

    f32x4 acc[4][4] = {};
#pragma unroll
    for (int ks = 0; ks < 8; ++ks) {
        h8 af[4], bf[4];
#pragma unroll
        for (int mi = 0; mi < 4; ++mi)
            af[mi] = *(const h8*)(A + (size_t)(rowBase + mi * 16 + l15) * 256 + ks * 32 + l4 * 8);
#pragma unroll
        for (int ni = 0; ni < 4; ++ni)
            bf[ni] = *(const h8*)(Wm1p + ((size_t)(ks * 4 + l4) * 64 + ni * 16 + l15) * 8);
#pragma unroll
        for (int mi = 0; mi < 4; ++mi)
#pragma unroll
            for (int ni = 0; ni < 4; ++ni)
                acc[mi][ni] = __builtin_amdgcn_mfma_f32_16x16x32_f16(af[mi], bf[ni], acc[mi][ni], 0, 0, 0);
    }
#pragma unroll
    for (int mi = 0; mi < 4; ++mi)
#pragma unroll
        for (int ni = 0; ni < 4; ++ni) {
            int c = ni * 16 + l15;
            float bv = bm1[c];
#pragma unroll
            for (int q = 0; q < 4; ++q)
                t1s[mi * 16 + l4 * 4 + q][c] = (_Float16)fmaxf(acc[mi][ni][q] + bv, 0.f);
        }

    f32x4 acc2[4][4] = {};
#pragma unroll
    for (int ks = 0; ks < 2; ++ks) {
        h8 af[4], bf[4];
#pragma unroll
        for (int mi = 0; mi < 4; ++mi)
            af[mi] = *(const h8*)&t1s[mi * 16 + l15][ks * 32 + l4 * 8];
#pragma unroll
        for (int ni = 0; ni < 4; ++ni)
            bf[ni] = *(const h8*)(Wm2p + ((size_t)(ks * 4 + l4) * 64 + ni * 16 + l15) * 8);
#pragma unroll
        for (int mi = 0; mi < 4; ++mi)
#pragma unroll
            for (int ni = 0; ni < 4; ++ni)
                acc2[mi][ni] = __builtin_amdgcn_mfma_f32_16x16x32_f16(af[mi], bf[ni], acc2[mi][ni], 0, 0, 0);
    }

    float b3 = bm3[0];
    float b2v[4], w3v[4];
#pragma unroll
    for (int ni = 0; ni < 4; ++ni) {
        b2v[ni] = bm2[ni * 16 + l15];
        w3v[ni] = Wm3[ni * 16 + l15];
    }
#pragma unroll
    for (int mi = 0; mi < 4; ++mi)
#pragma unroll
        for (int q = 0; q < 4; ++q) {
            float part = 0.f;
#pragma unroll
            for (int ni = 0; ni < 4; ++ni)
                part += fmaxf(acc2[mi][ni][q] + b2v[ni], 0.f) * w3v[ni];
            part += __shfl_xor(part, 1);
            part += __shfl_xor(part, 2);
            part += __shfl_xor(part, 4);
            part += __shfl_xor(part, 8);
            if (l15 == 0)
                out[rowBase + mi * 16 + l4 * 4 + q] = part + b3;
        }
}

// ---------------------------------------------------------------------------
extern "C" void kernel_launch(void* const* d_in, const int* in_sizes, int n_in,
                              void* d_out, int out_size, void* d_ws, size_t ws_size,
                              hipStream_t stream) {
    const float* x     = (const float*)d_in[0];
    const int*   ei    = (const int*)d_in[1];
    const float* Win   = (const float*)d_in[2];
    const float* b_in  = (const float*)d_in[3];
    const float* Wskip = (const float*)d_in[4];
    const float* bskip = (const float*)d_in[5];
    const float* Wl1   = (const float*)d_in[6];
    const float* Wr1   = (const float*)d_in[7];
    const float* att1  = (const float*)d_in[8];
    const float* b1    = (const float*)d_in[9];
    const float* Wl2   = (const float*)d_in[10];
    const float* Wr2   = (const float*)d_in[11];
    const float* att2  = (const float*)d_in[12];
    const float* b2    = (const float*)d_in[13];
    const float* Wl3   = (const float*)d_in[14];
    const float* Wr3   = (const float*)d_in[15];
    const float* att3  = (const float*)d_in[16];
    const float* b3    = (const float*)d_in[17];
    const float* Wm1   = (const float*)d_in[18];
    const float* bm1   = (const float*)d_in[19];
    const float* Wm2   = (const float*)d_in[20];
    const float* bm2   = (const float*)d_in[21];
    const float* Wm3   = (const float*)d_in[22];
    const float* bm3   = (const float*)d_in[23];

    // ---- workspace layout ----
    char* p = (char*)d_ws;
    auto alloc = [&](size_t bytes) { char* r = p; p += (bytes + 255) & ~(size_t)255; return r; };
    const size_t NN = N_NODES;
    float*    skip = (float*)alloc(NN * 256 * 4);   // also out2
    float*    out1 = (float*)alloc(NN * 256 * 4);
    _Float16* o116 = (_Float16*)alloc(NN * 256 * 2);
    _Float16* o216 = (_Float16*)alloc(NN * 256 * 2);
    _Float16* o316 = o116;                          // o116 dead by gat3
    _Float16* h16  = (_Float16*)alloc(NN * 64 * 2);
    _Float16* xl16 = (_Float16*)alloc(NN * 256 * 2);
    _Float16* xr16 = (_Float16*)alloc(NN * 256 * 2);
    _Float16* Wp1  = (_Float16*)alloc((size_t)64 * 768 * 2);
    _Float16* Wp2  = (_Float16*)alloc((size_t)256 * 512 * 2);
    _Float16* Wp3  = (_Float16*)alloc((size_t)256 * 512 * 2);
    _Float16* Winp = (_Float16*)alloc((size_t)128 * 64 * 2);
    _Float16* Wm1p = (_Float16*)alloc((size_t)256 * 64 * 2);
    _Float16* Wm2p = (_Float16*)alloc((size_t)64 * 64 * 2);
    int* cnt    = (int*)alloc(N_NODES * 4);
    int* offs   = (int*)alloc((N_NODES + 1) * 4);
    int* cursor = (int*)alloc(N_NODES * 4);
    int* esrc   = (int*)alloc(E_EDGES * 4);

    const int* src = ei;
    const int* dst = ei + E_EDGES;

    // ---- CSR build ----
    zero_cnt_kernel<<<N_NODES / 1024, 256, 0, stream>>>((int4*)cnt);
    hist_kernel<<<E_EDGES / 256, 256, 0, stream>>>(dst, cnt);
    csr_scan_kernel<<<1, 256, 0, stream>>>(cnt, offs, cursor);
    scatter_kernel<<<E_EDGES / 256, 256, 0, stream>>>(src, dst, cursor, esrc);

    // ---- pack all weights (one launch) ----
    PackJobs jobs = {{
        { Wl1,   Wp1,  64,  256, 768, 0   },
        { Wr1,   Wp1,  64,  256, 768, 256 },
        { Wskip, Wp1,  64,  256, 768, 512 },
        { Wl2,   Wp2,  256, 256, 512, 0   },
        { Wr2,   Wp2,  256, 256, 512, 256 },
        { Wl3,   Wp3,  256, 256, 512, 0   },
        { Wr3,   Wp3,  256, 256, 512, 256 },
        { Win,   Winp, 128, 64,  64,  0   },
        { Wm1,   Wm1p, 256, 64,  64,  0   },
        { Wm2,   Wm2p, 64,  64,  64,  0   },
    }};
    pack_all_kernel<<<dim3(256, 10), 256, 0, stream>>>(jobs);

    // ---- input proj: h16 = fp16(relu(x @ Win + b_in)), cast fused ----
    mfma_n64_kernel<128, true, true, true><<<N_NODES / 64, 64, 0, stream>>>(x, Winp, b_in, h16);

    // ---- conv1: xl|xr|skip in one MFMA GEMM ----
    mfma_gemm_kernel<64><<<dim3(128, 6), 256, 0, stream>>>(h16, Wp1, 768, xl16, xr16, skip, bskip);
    gat_agg_kernel<4, 1><<<N_NODES / 4, 256, 0, stream>>>(xl16, xr16, att1, b1, skip, offs, esrc, out1, o116);

    // ---- conv2 ----
    mfma_gemm_kernel<256><<<dim3(128, 4), 256, 0, stream>>>(o116, Wp2, 512, xl16, xr16, nullptr, nullptr);
    gat_agg_kernel<1, 1><<<N_NODES / 4, 256, 0, stream>>>(xl16, xr16, att2, b2, out1, offs, esrc, skip /*out2*/, o216);

    // ---- conv3 (fp16-only output) ----
    mfma_gemm_kernel<256><<<dim3(128, 4), 256, 0, stream>>>(o216, Wp3, 512, xl16, xr16, nullptr, nullptr);
    gat_agg_kernel<1, 2><<<N_NODES / 4, 256, 0, stream>>>(xl16, xr16, att3, b3, skip /*out2*/, offs, esrc, nullptr, o316);

    // ---- fused MLP head ----
    mlp_head_kernel<<<N_NODES / 64, 64, 0, stream>>>(o316, Wm1p, bm1, Wm2p, bm2, Wm3, bm3, (float*)d_out);
}